// Round 2
// baseline (1549.911 us; speedup 1.0000x reference)
//
#include <hip/hip_runtime.h>

typedef short s16x8 __attribute__((ext_vector_type(8)));
typedef unsigned short u16x8 __attribute__((ext_vector_type(8)));
typedef unsigned short u16x4 __attribute__((ext_vector_type(4)));
typedef float f32x4 __attribute__((ext_vector_type(4)));

#define CB 2
#define CS 4096
#define CD 2048
#define CH 16
#define CSEG 512
#define CDH 8192

__device__ __forceinline__ unsigned short f2b(float f) {
  union { float f; unsigned u; } v; v.f = f;
  unsigned r = v.u + 0x7fffu + ((v.u >> 16) & 1u);
  return (unsigned short)(r >> 16);
}
__device__ __forceinline__ float b2f(unsigned short b) {
  union { unsigned u; float f; } v; v.u = ((unsigned)b) << 16;
  return v.f;
}
__device__ __forceinline__ f32x4 mfma16(s16x8 a, s16x8 b, f32x4 c) {
  return __builtin_amdgcn_mfma_f32_16x16x32_bf16(a, b, c, 0, 0, 0);
}
__device__ __forceinline__ void async16(const unsigned short* g, unsigned short* l) {
  __builtin_amdgcn_global_load_lds((const __attribute__((address_space(1))) void*)g,
                                   (__attribute__((address_space(3))) void*)l, 16, 0, 0);
}

// ---------------- fp32 -> bf16 convert ----------------
__global__ void convert_bf16_k(const float* __restrict__ in, unsigned short* __restrict__ out) {
  size_t i = ((size_t)blockIdx.x * 256 + threadIdx.x) * 4;
  f32x4 v = *(const f32x4*)(in + i);
  u16x4 o;
  #pragma unroll
  for (int e = 0; e < 4; e++) o[e] = f2b(v[e]);
  *(u16x4*)(out + i) = o;
}

// ---------------- fp32 RxC -> bf16 CxR transpose ----------------
__global__ void transpose_bf16_k(const float* __restrict__ in, unsigned short* __restrict__ out,
                                 int R, int C) {
  __shared__ float tile[32][33];
  int c0 = blockIdx.x * 32, r0 = blockIdx.y * 32;
  int tx = threadIdx.x & 31, ty = threadIdx.x >> 5;
  #pragma unroll
  for (int i = 0; i < 32; i += 8)
    tile[ty + i][tx] = in[(size_t)(r0 + ty + i) * C + c0 + tx];
  __syncthreads();
  #pragma unroll
  for (int i = 0; i < 32; i += 8)
    out[(size_t)(c0 + ty + i) * R + r0 + tx] = f2b(tile[tx][ty + i]);
}

// ---------------- GEMM: C[M,N] = A[M,K] @ BT[N,K]^T (bf16 in, MFMA) ----------------
// EPI: 1 = bf16 out, 2 = bias+relu bf16 out, 3 = bias fp32 out
template <int EPI>
__global__ void gemm_bt(const unsigned short* __restrict__ A,
                        const unsigned short* __restrict__ BT,
                        const float* __restrict__ bias,
                        void* __restrict__ Cp, int M, int N, int K) {
  __shared__ unsigned short As[128 * 32];
  __shared__ unsigned short Bs[128 * 32];
  const int t = threadIdx.x, wave = t >> 6, lane = t & 63;
  const int fr = lane & 15, fq = (lane >> 4) * 8;
  const int m0 = blockIdx.x * 128, n0 = blockIdx.y * 128;
  const int wr = (wave >> 1) * 64, wc = (wave & 1) * 64;
  const int srow = lane >> 2, scol = (lane & 3) * 8;

  f32x4 acc[4][4] = {};

  const unsigned short* Ag = A + (size_t)(m0 + wave * 32 + srow) * K + scol;
  const unsigned short* Bg = BT + (size_t)(n0 + wave * 32 + srow) * K + scol;
  unsigned short* Al = As + (wave * 32) * 32;
  unsigned short* Bl = Bs + (wave * 32) * 32;
  const size_t r16 = (size_t)16 * K;

  for (int kk = 0; kk < K; kk += 32) {
    __syncthreads();
    async16(Ag + kk, Al);
    async16(Ag + kk + r16, Al + 16 * 32);
    async16(Bg + kk, Bl);
    async16(Bg + kk + r16, Bl + 16 * 32);
    __syncthreads();
    s16x8 af[4], bfr[4];
    #pragma unroll
    for (int i = 0; i < 4; i++) af[i] = *(const s16x8*)&As[(wr + i * 16 + fr) * 32 + fq];
    #pragma unroll
    for (int j = 0; j < 4; j++) bfr[j] = *(const s16x8*)&Bs[(wc + j * 16 + fr) * 32 + fq];
    #pragma unroll
    for (int i = 0; i < 4; i++)
      #pragma unroll
      for (int j = 0; j < 4; j++)
        acc[i][j] = mfma16(af[i], bfr[j], acc[i][j]);
  }

  const int er = (lane >> 4) * 4, ec = lane & 15;
  #pragma unroll
  for (int i = 0; i < 4; i++) {
    int row = m0 + wr + i * 16 + er;
    #pragma unroll
    for (int j = 0; j < 4; j++) {
      int col = n0 + wc + j * 16 + ec;
      float bv = (EPI >= 2) ? bias[col] : 0.f;
      #pragma unroll
      for (int r = 0; r < 4; r++) {
        float v = acc[i][j][r];
        size_t idx = (size_t)(row + r) * N + col;
        if (EPI == 1) ((unsigned short*)Cp)[idx] = f2b(v);
        else if (EPI == 2) { v += bv; ((unsigned short*)Cp)[idx] = f2b(v > 0.f ? v : 0.f); }
        else { v += bv; ((float*)Cp)[idx] = v; }
      }
    }
  }
}

// ---------------- per-segment KV sums: memsegT[v][d] = sum_s v[s][v]*sigk[s][d] ----------------
__global__ void kvsum_k(const unsigned short* __restrict__ kb, const unsigned short* __restrict__ vb,
                        float* __restrict__ memsegT, float* __restrict__ zseg) {
  const int seg = blockIdx.x, b = blockIdx.y, h = blockIdx.z;
  const int t = threadIdx.x;
  __shared__ float sk[32 * 128];
  __shared__ float sv[32 * 128];
  float acc[8][8] = {};
  float z = 0.f;
  const int vb0 = (t & 15) * 8, db0 = (t >> 4) * 8;
  const size_t base = ((size_t)b * CS + (size_t)seg * CSEG) * CD + (size_t)h * 128;

  for (int st = 0; st < 16; st++) {
    __syncthreads();
    {
      int row = t >> 3, c0 = (t & 7) * 16;
      size_t g = base + (size_t)(st * 32 + row) * CD + c0;
      #pragma unroll
      for (int u = 0; u < 2; u++) {
        u16x8 kv = *(const u16x8*)(kb + g + u * 8);
        u16x8 vv = *(const u16x8*)(vb + g + u * 8);
        #pragma unroll
        for (int e = 0; e < 8; e++) {
          float kf = b2f(kv[e]);
          sk[row * 128 + c0 + u * 8 + e] = kf > 0.f ? kf + 1.f : __expf(kf);
          sv[row * 128 + c0 + u * 8 + e] = b2f(vv[e]);
        }
      }
    }
    __syncthreads();
    #pragma unroll 2
    for (int s = 0; s < 32; s++) {
      f32x4 a0 = *(const f32x4*)&sv[s * 128 + vb0];
      f32x4 a1 = *(const f32x4*)&sv[s * 128 + vb0 + 4];
      f32x4 d0 = *(const f32x4*)&sk[s * 128 + db0];
      f32x4 d1 = *(const f32x4*)&sk[s * 128 + db0 + 4];
      float av[8] = {a0[0], a0[1], a0[2], a0[3], a1[0], a1[1], a1[2], a1[3]};
      float ad[8] = {d0[0], d0[1], d0[2], d0[3], d1[0], d1[1], d1[2], d1[3]};
      #pragma unroll
      for (int i = 0; i < 8; i++)
        #pragma unroll
        for (int j = 0; j < 8; j++)
          acc[i][j] += av[i] * ad[j];
    }
    if (t < 128) {
      #pragma unroll 4
      for (int s = 0; s < 32; s++) z += sk[s * 128 + t];
    }
  }
  const size_t obase = (size_t)((seg * 2 + b) * 16 + h) * 16384;
  #pragma unroll
  for (int i = 0; i < 8; i++)
    #pragma unroll
    for (int j = 0; j < 8; j++)
      memsegT[obase + (size_t)(vb0 + i) * 128 + db0 + j] = acc[i][j];
  if (t < 128) zseg[(size_t)((seg * 2 + b) * 16 + h) * 128 + t] = z;
}

// ---------------- exclusive prefix over segments ----------------
__global__ void prefix_k(const float* __restrict__ memsegT, const float* __restrict__ zseg,
                         unsigned short* __restrict__ memPT, float* __restrict__ zP) {
  const int bh = blockIdx.x, t = threadIdx.x;
  for (int e = t; e < 16384; e += 256) {
    float a = 0.f;
    #pragma unroll
    for (int s = 0; s < 8; s++) {
      size_t idx = (size_t)(s * 32 + bh) * 16384 + e;
      memPT[idx] = f2b(a);
      a += memsegT[idx];
    }
  }
  if (t < 128) {
    float a = 1.f / 128.f;
    #pragma unroll
    for (int s = 0; s < 8; s++) {
      size_t idx = (size_t)(s * 32 + bh) * 128 + t;
      zP[idx] = a;
      a += zseg[idx];
    }
  }
}

// ---------------- fused segment attention (flash) + memory retrieval + gate ----------------
#define PD 136
#define PPS 40
__global__ void attn_k(const unsigned short* __restrict__ qb,
                       const unsigned short* __restrict__ kb,
                       const unsigned short* __restrict__ vb,
                       const unsigned short* __restrict__ memPT,
                       const float* __restrict__ zPv,
                       const float* __restrict__ betas,
                       unsigned short* __restrict__ att) {
  const int qt = blockIdx.x, seg = blockIdx.y, bh = blockIdx.z;
  const int b = bh >> 4, h = bh & 15;
  const int t = threadIdx.x, wave = t >> 6, lane = t & 63;
  const int fr = lane & 15, quad = lane >> 4, fq = quad * 8;

  __shared__ unsigned short Qs[64 * PD];
  __shared__ unsigned short SB[64 * PD];   // sig_q, later P
  __shared__ unsigned short KVb[64 * PD];  // mem quarters, later K|V tiles
  __shared__ float denomS[64];
  __shared__ float zPs[128];

  unsigned short* SQ = SB;
  unsigned short* Ps = SB;
  unsigned short* KB = KVb;
  unsigned short* VB = KVb + 32 * PD;

  const size_t qrow0 = (size_t)b * CS + (size_t)seg * CSEG + (size_t)qt * 64;
  const size_t mbase = (size_t)(seg * 32 + bh) * 16384;

  // stage Q (pre-scaled) and sig_q
  {
    int row = t >> 2, c0 = (t & 3) * 32;
    const unsigned short* src = qb + (qrow0 + row) * (size_t)CD + (size_t)h * 128 + c0;
    #pragma unroll
    for (int u = 0; u < 4; u++) {
      u16x8 qv = *(const u16x8*)(src + u * 8);
      u16x8 qo, so;
      #pragma unroll
      for (int e = 0; e < 8; e++) {
        float f = b2f(qv[e]);
        qo[e] = f2b(f * 0.08838834764831845f);
        so[e] = f2b(f > 0.f ? f + 1.f : __expf(f));
      }
      *(u16x8*)&Qs[row * PD + c0 + u * 8] = qo;
      *(u16x8*)&SQ[row * PD + c0 + u * 8] = so;
    }
    if (t < 128) zPs[t] = zPv[(size_t)(seg * 32 + bh) * 128 + t];
  }
  __syncthreads();

  // denominators: sig_q . zP
  if (t < 64) {
    float s = 0.f;
    for (int i = 0; i < 128; i++) {
      int d = (t * 2 + i) & 127;
      s += b2f(SQ[t * PD + d]) * zPs[d];
    }
    denomS[t] = s;
  }

  // att_mem = sig_q @ memP  (memP staged in 32-row quarters)
  f32x4 om[8] = {};
  for (int qd = 0; qd < 4; qd++) {
    __syncthreads();
    {
      int row = t >> 3, c0 = (t & 7) * 16;
      const unsigned short* msrc = memPT + mbase + (size_t)(qd * 32 + row) * 128 + c0;
      *(u16x8*)&KB[row * PD + c0] = *(const u16x8*)msrc;
      *(u16x8*)&KB[row * PD + c0 + 8] = *(const u16x8*)(msrc + 8);
    }
    __syncthreads();
    #pragma unroll
    for (int jj = 0; jj < 2; jj++)
      #pragma unroll
      for (int kf = 0; kf < 4; kf++) {
        s16x8 a = *(const s16x8*)&SQ[(wave * 16 + fr) * PD + kf * 32 + fq];
        s16x8 bb = *(const s16x8*)&KB[(jj * 16 + fr) * PD + kf * 32 + fq];
        om[qd * 2 + jj] = mfma16(a, bb, om[qd * 2 + jj]);
      }
  }

  // causal attention, online softmax, 32-key tiles
  f32x4 od[8] = {};
  float mrow[4], lrow[4];
  #pragma unroll
  for (int r = 0; r < 4; r++) { mrow[r] = -1e30f; lrow[r] = 0.f; }

  const int nkt = qt * 2 + 2;
  for (int kt = 0; kt < nkt; kt++) {
    __syncthreads();
    {
      int row = t >> 3, c0 = (t & 7) * 16;
      size_t g = ((size_t)b * CS + (size_t)seg * CSEG + (size_t)kt * 32 + row) * CD + (size_t)h * 128 + c0;
      *(u16x8*)&KB[row * PD + c0] = *(const u16x8*)(kb + g);
      *(u16x8*)&KB[row * PD + c0 + 8] = *(const u16x8*)(kb + g + 8);
      *(u16x8*)&VB[row * PD + c0] = *(const u16x8*)(vb + g);
      *(u16x8*)&VB[row * PD + c0 + 8] = *(const u16x8*)(vb + g + 8);
    }
    __syncthreads();

    f32x4 sc[2] = {};
    #pragma unroll
    for (int kf = 0; kf < 4; kf++) {
      s16x8 a = *(const s16x8*)&Qs[(wave * 16 + fr) * PD + kf * 32 + fq];
      #pragma unroll
      for (int nt = 0; nt < 2; nt++) {
        s16x8 bb = *(const s16x8*)&KB[(nt * 16 + fr) * PD + kf * 32 + fq];
        sc[nt] = mfma16(a, bb, sc[nt]);
      }
    }

    if (kt >= 2 * qt) {
      #pragma unroll
      for (int nt = 0; nt < 2; nt++)
        #pragma unroll
        for (int r = 0; r < 4; r++) {
          int qi = qt * 64 + wave * 16 + quad * 4 + r;
          int ki = kt * 32 + nt * 16 + fr;
          if (ki > qi) sc[nt][r] = -1e30f;
        }
    }

    float al[4], pv[2][4];
    #pragma unroll
    for (int r = 0; r < 4; r++) {
      float mx = fmaxf(sc[0][r], sc[1][r]);
      #pragma unroll
      for (int xm = 8; xm >= 1; xm >>= 1) mx = fmaxf(mx, __shfl_xor(mx, xm, 64));
      float mn = fmaxf(mrow[r], mx);
      al[r] = __expf(mrow[r] - mn);
      mrow[r] = mn;
      float ps = 0.f;
      #pragma unroll
      for (int nt = 0; nt < 2; nt++) {
        float p = __expf(sc[nt][r] - mn);
        pv[nt][r] = p;
        ps += p;
      }
      #pragma unroll
      for (int xm = 8; xm >= 1; xm >>= 1) ps += __shfl_xor(ps, xm, 64);
      lrow[r] = lrow[r] * al[r] + ps;
    }
    #pragma unroll
    for (int j = 0; j < 8; j++)
      #pragma unroll
      for (int r = 0; r < 4; r++) od[j][r] *= al[r];

    #pragma unroll
    for (int nt = 0; nt < 2; nt++)
      #pragma unroll
      for (int r = 0; r < 4; r++)
        Ps[(wave * 16 + quad * 4 + r) * PPS + nt * 16 + fr] = f2b(pv[nt][r]);

    s16x8 a = *(const s16x8*)&Ps[(wave * 16 + fr) * PPS + fq];
    #pragma unroll
    for (int j = 0; j < 8; j++) {
      s16x8 bb;
      #pragma unroll
      for (int e = 0; e < 8; e++)
        bb[e] = (short)VB[(fq + e) * PD + j * 16 + fr];
      od[j] = mfma16(a, bb, od[j]);
    }
  }

  // gate-combine epilogue
  #pragma unroll
  for (int j = 0; j < 8; j++) {
    int vcol = j * 16 + fr;
    float g = 1.f / (1.f + __expf(-betas[h * 128 + vcol]));
    #pragma unroll
    for (int r = 0; r < 4; r++) {
      int rowl = wave * 16 + quad * 4 + r;
      float amem = om[j][r] / denomS[rowl];
      float adot = od[j][r] / lrow[r];
      att[(qrow0 + rowl) * (size_t)CD + (size_t)h * 128 + vcol] = f2b(g * amem + (1.f - g) * adot);
    }
  }
}

// ---------------- residual + LayerNorm ----------------
__global__ void ln_k(const float* __restrict__ y, const float* __restrict__ x,
                     const float* __restrict__ gam, const float* __restrict__ bet,
                     float* __restrict__ out) {
  const int row = blockIdx.x, t = threadIdx.x;
  const int lane = t & 63, wave = t >> 6;
  const float* yr = y + (size_t)row * CD;
  const float* xr = x + (size_t)row * CD;
  float v[8];
  float s = 0.f, ss = 0.f;
  #pragma unroll
  for (int u = 0; u < 2; u++) {
    f32x4 a = *(const f32x4*)(yr + t * 8 + u * 4);
    f32x4 c = *(const f32x4*)(xr + t * 8 + u * 4);
    #pragma unroll
    for (int e = 0; e < 4; e++) {
      float r = a[e] + c[e];
      v[u * 4 + e] = r; s += r; ss += r * r;
    }
  }
  #pragma unroll
  for (int off = 32; off >= 1; off >>= 1) {
    s += __shfl_xor(s, off, 64);
    ss += __shfl_xor(ss, off, 64);
  }
  __shared__ float red[8];
  if (lane == 0) { red[wave] = s; red[4 + wave] = ss; }
  __syncthreads();
  s = red[0] + red[1] + red[2] + red[3];
  ss = red[4] + red[5] + red[6] + red[7];
  const float mu = s * (1.f / 2048.f);
  const float var = ss * (1.f / 2048.f) - mu * mu;
  const float rs = rsqrtf(var + 1e-5f);
  #pragma unroll
  for (int u = 0; u < 2; u++)
    #pragma unroll
    for (int e = 0; e < 4; e++) {
      int c = t * 8 + u * 4 + e;
      out[(size_t)row * CD + c] = (v[u * 4 + e] - mu) * rs * gam[c] + bet[c];
    }
}

extern "C" void kernel_launch(void* const* d_in, const int* in_sizes, int n_in,
                              void* d_out, int out_size, void* d_ws, size_t ws_size,
                              hipStream_t stream) {
  const float* xf   = (const float*)d_in[0];
  const float* Wq   = (const float*)d_in[1];
  const float* Wk   = (const float*)d_in[2];
  const float* Wv   = (const float*)d_in[3];
  const float* Wo   = (const float*)d_in[4];
  const float* bet  = (const float*)d_in[5];
  const float* W1   = (const float*)d_in[6];
  const float* b1   = (const float*)d_in[7];
  const float* W2   = (const float*)d_in[8];
  const float* b2   = (const float*)d_in[9];
  const float* lng  = (const float*)d_in[10];
  const float* lnb  = (const float*)d_in[11];
  float* out = (float*)d_out;

  // ---- tight 224 MB workspace layout with lifetime-based overlays ----
  const size_t MB = 1024ull * 1024ull;
  char* w = (char*)d_ws;
  unsigned short* qbuf  = (unsigned short*)(w + 0 * MB);    // 32MB, dead after attn/Wo path
  unsigned short* kbuf  = (unsigned short*)(w + 32 * MB);   // 32MB
  unsigned short* vbuf  = (unsigned short*)(w + 64 * MB);   // 32MB
  unsigned short* xb    = (unsigned short*)(w + 96 * MB);   // 32MB, dead after QKV gemms
  unsigned short* attb  = (unsigned short*)(w + 96 * MB);   // overlays xb (written by attn)
  float*          msegT = (float*)(w + 128 * MB);           // 16MB, dead after prefix
  unsigned short* memPT = (unsigned short*)(w + 144 * MB);  // 8MB, dead after attn
  float*          zsegb = (float*)(w + 152 * MB);           // 128KB
  float*          zPb   = (float*)(w + 153 * MB);           // 128KB
  unsigned short* aob   = (unsigned short*)(w + 128 * MB);  // 32MB, overlays mseg/memP/z (post-attn)
  unsigned short* W1T   = (unsigned short*)(w + 160 * MB);  // 32MB, dead after W1 gemm
  unsigned short* WqT   = (unsigned short*)(w + 192 * MB);  // 8MB
  unsigned short* WkT   = (unsigned short*)(w + 200 * MB);  // 8MB
  unsigned short* WvT   = (unsigned short*)(w + 208 * MB);  // 8MB
  unsigned short* WoT   = (unsigned short*)(w + 216 * MB);  // 8MB, all dead after Wo gemm
  unsigned short* W2T   = (unsigned short*)(w + 192 * MB);  // 32MB, overlays WqT..WoT (post-Wo)
  unsigned short* hb    = (unsigned short*)(w + 0 * MB);    // 128MB, overlays q/k/v/attb (post-Wo)
  float*          yb    = (float*)(w + 128 * MB);           // 64MB, overlays aob+W1T (post-W1)

  convert_bf16_k<<<dim3(16384), 256, 0, stream>>>(xf, xb);
  transpose_bf16_k<<<dim3(64, 64), 256, 0, stream>>>(Wq, WqT, 2048, 2048);
  transpose_bf16_k<<<dim3(64, 64), 256, 0, stream>>>(Wk, WkT, 2048, 2048);
  transpose_bf16_k<<<dim3(64, 64), 256, 0, stream>>>(Wv, WvT, 2048, 2048);
  transpose_bf16_k<<<dim3(64, 64), 256, 0, stream>>>(Wo, WoT, 2048, 2048);
  transpose_bf16_k<<<dim3(256, 64), 256, 0, stream>>>(W1, W1T, 2048, 8192);

  gemm_bt<1><<<dim3(64, 16), 256, 0, stream>>>(xb, WqT, nullptr, qbuf, 8192, 2048, 2048);
  gemm_bt<1><<<dim3(64, 16), 256, 0, stream>>>(xb, WkT, nullptr, kbuf, 8192, 2048, 2048);
  gemm_bt<1><<<dim3(64, 16), 256, 0, stream>>>(xb, WvT, nullptr, vbuf, 8192, 2048, 2048);

  kvsum_k<<<dim3(8, 2, 16), 256, 0, stream>>>(kbuf, vbuf, msegT, zsegb);
  prefix_k<<<dim3(32), 256, 0, stream>>>(msegT, zsegb, memPT, zPb);
  attn_k<<<dim3(8, 8, 32), 256, 0, stream>>>(qbuf, kbuf, vbuf, memPT, zPb, bet, attb);

  gemm_bt<1><<<dim3(64, 16), 256, 0, stream>>>(attb, WoT, nullptr, aob, 8192, 2048, 2048);
  transpose_bf16_k<<<dim3(64, 256), 256, 0, stream>>>(W2, W2T, 8192, 2048);
  gemm_bt<2><<<dim3(64, 64), 256, 0, stream>>>(aob, W1T, b1, hb, 8192, 8192, 2048);
  gemm_bt<3><<<dim3(64, 16), 256, 0, stream>>>(hb, W2T, b2, yb, 8192, 2048, 8192);
  ln_k<<<dim3(8192), 256, 0, stream>>>(yb, xf, lng, lnb, out);
}

// Round 3
// 1474.874 us; speedup vs baseline: 1.0509x; 1.0509x over previous
//
#include <hip/hip_runtime.h>

typedef short s16x8 __attribute__((ext_vector_type(8)));
typedef unsigned short u16x8 __attribute__((ext_vector_type(8)));
typedef unsigned short u16x4 __attribute__((ext_vector_type(4)));
typedef float f32x4 __attribute__((ext_vector_type(4)));

#define CB 2
#define CS 4096
#define CD 2048
#define CH 16
#define CSEG 512
#define CDH 8192

__device__ __forceinline__ unsigned short f2b(float f) {
  union { float f; unsigned u; } v; v.f = f;
  unsigned r = v.u + 0x7fffu + ((v.u >> 16) & 1u);
  return (unsigned short)(r >> 16);
}
__device__ __forceinline__ float b2f(unsigned short b) {
  union { unsigned u; float f; } v; v.u = ((unsigned)b) << 16;
  return v.f;
}
__device__ __forceinline__ f32x4 mfma16(s16x8 a, s16x8 b, f32x4 c) {
  return __builtin_amdgcn_mfma_f32_16x16x32_bf16(a, b, c, 0, 0, 0);
}
__device__ __forceinline__ void async16(const unsigned short* g, unsigned short* l) {
  __builtin_amdgcn_global_load_lds((const __attribute__((address_space(1))) void*)g,
                                   (__attribute__((address_space(3))) void*)l, 16, 0, 0);
}

// ---------------- fp32 -> bf16 convert ----------------
__global__ void convert_bf16_k(const float* __restrict__ in, unsigned short* __restrict__ out) {
  size_t i = ((size_t)blockIdx.x * 256 + threadIdx.x) * 4;
  f32x4 v = *(const f32x4*)(in + i);
  u16x4 o;
  #pragma unroll
  for (int e = 0; e < 4; e++) o[e] = f2b(v[e]);
  *(u16x4*)(out + i) = o;
}

// ---------------- fp32 RxC -> bf16 CxR transpose ----------------
__global__ void transpose_bf16_k(const float* __restrict__ in, unsigned short* __restrict__ out,
                                 int R, int C) {
  __shared__ float tile[32][33];
  int c0 = blockIdx.x * 32, r0 = blockIdx.y * 32;
  int tx = threadIdx.x & 31, ty = threadIdx.x >> 5;
  #pragma unroll
  for (int i = 0; i < 32; i += 8)
    tile[ty + i][tx] = in[(size_t)(r0 + ty + i) * C + c0 + tx];
  __syncthreads();
  #pragma unroll
  for (int i = 0; i < 32; i += 8)
    out[(size_t)(c0 + ty + i) * R + r0 + tx] = f2b(tile[tx][ty + i]);
}

// ---- bf16 [B*S, 2048] -> per-(b,h) transposed [ (b*16+h)*128+v ][4096 s ]; K gets elu+1 ----
__global__ void transpose_kv_k(const unsigned short* __restrict__ kb,
                               const unsigned short* __restrict__ vb,
                               unsigned short* __restrict__ KT,
                               unsigned short* __restrict__ VT) {
  __shared__ unsigned short kt_[64][72];  // 144 B rows (16B-aligned)
  __shared__ unsigned short vt_[64][72];
  const int t = threadIdx.x;
  const int r0 = blockIdx.x * 64, c0 = blockIdx.y * 64;
  {
    int row = t >> 2, cc = (t & 3) * 16;
    size_t g = (size_t)(r0 + row) * CD + c0 + cc;
    #pragma unroll
    for (int u = 0; u < 2; u++) {
      u16x8 kv = *(const u16x8*)(kb + g + u * 8);
      u16x8 vv = *(const u16x8*)(vb + g + u * 8);
      u16x8 ko;
      #pragma unroll
      for (int e = 0; e < 8; e++) {
        float f = b2f(kv[e]);
        ko[e] = f2b(f > 0.f ? f + 1.f : __expf(f));
      }
      *(u16x8*)&kt_[row][cc + u * 8] = ko;
      *(u16x8*)&vt_[row][cc + u * 8] = vv;
    }
  }
  __syncthreads();
  {
    int vc = t >> 2, s0 = (t & 3) * 16;
    int c = c0 + vc;
    int h = c >> 7, v = c & 127;
    int b = r0 >> 12, sbase = (r0 & 4095) + s0;
    size_t obase = ((size_t)((b * 16 + h) * 128 + v) << 12) + sbase;
    u16x8 wk0, wk1, wv0, wv1;
    #pragma unroll
    for (int e = 0; e < 8; e++) {
      wk0[e] = kt_[s0 + e][vc];      wv0[e] = vt_[s0 + e][vc];
      wk1[e] = kt_[s0 + 8 + e][vc];  wv1[e] = vt_[s0 + 8 + e][vc];
    }
    *(u16x8*)&KT[obase] = wk0;  *(u16x8*)&KT[obase + 8] = wk1;
    *(u16x8*)&VT[obase] = wv0;  *(u16x8*)&VT[obase + 8] = wv1;
  }
}

// ---------------- GEMM: C[M,N] = A[M,K] @ BT[N,K]^T (bf16 in, MFMA) ----------------
// EPI: 1 = bf16 out, 2 = bias+relu bf16 out, 4 = bias bf16 out
template <int EPI>
__global__ void gemm_bt(const unsigned short* __restrict__ A,
                        const unsigned short* __restrict__ BT,
                        const float* __restrict__ bias,
                        void* __restrict__ Cp, int M, int N, int K) {
  __shared__ unsigned short As[128 * 32];
  __shared__ unsigned short Bs[128 * 32];
  const int t = threadIdx.x, wave = t >> 6, lane = t & 63;
  const int fr = lane & 15, fq = (lane >> 4) * 8;
  // L2-locality supertile swizzle: stripes of 8 m-blocks, walk n within a stripe
  const int nbx = gridDim.x, nby = gridDim.y;
  int flat = blockIdx.x + blockIdx.y * nbx;
  int stripe = flat / (8 * nby);
  int rem = flat % (8 * nby);
  const int m0 = (stripe * 8 + (rem & 7)) * 128, n0 = (rem >> 3) * 128;
  const int wr = (wave >> 1) * 64, wc = (wave & 1) * 64;
  const int srow = lane >> 2, scol = (lane & 3) * 8;

  f32x4 acc[4][4] = {};

  const unsigned short* Ag = A + (size_t)(m0 + wave * 32 + srow) * K + scol;
  const unsigned short* Bg = BT + (size_t)(n0 + wave * 32 + srow) * K + scol;
  unsigned short* Al = As + (wave * 32) * 32;
  unsigned short* Bl = Bs + (wave * 32) * 32;
  const size_t r16 = (size_t)16 * K;

  for (int kk = 0; kk < K; kk += 32) {
    __syncthreads();
    async16(Ag + kk, Al);
    async16(Ag + kk + r16, Al + 16 * 32);
    async16(Bg + kk, Bl);
    async16(Bg + kk + r16, Bl + 16 * 32);
    __syncthreads();
    s16x8 af[4], bfr[4];
    #pragma unroll
    for (int i = 0; i < 4; i++) af[i] = *(const s16x8*)&As[(wr + i * 16 + fr) * 32 + fq];
    #pragma unroll
    for (int j = 0; j < 4; j++) bfr[j] = *(const s16x8*)&Bs[(wc + j * 16 + fr) * 32 + fq];
    #pragma unroll
    for (int i = 0; i < 4; i++)
      #pragma unroll
      for (int j = 0; j < 4; j++)
        acc[i][j] = mfma16(af[i], bfr[j], acc[i][j]);
  }

  const int er = (lane >> 4) * 4, ec = lane & 15;
  #pragma unroll
  for (int i = 0; i < 4; i++) {
    int row = m0 + wr + i * 16 + er;
    #pragma unroll
    for (int j = 0; j < 4; j++) {
      int col = n0 + wc + j * 16 + ec;
      float bv = (EPI >= 2) ? bias[col] : 0.f;
      #pragma unroll
      for (int r = 0; r < 4; r++) {
        float v = acc[i][j][r];
        size_t idx = (size_t)(row + r) * N + col;
        if (EPI == 1) ((unsigned short*)Cp)[idx] = f2b(v);
        else if (EPI == 2) { v += bv; ((unsigned short*)Cp)[idx] = f2b(v > 0.f ? v : 0.f); }
        else { v += bv; ((unsigned short*)Cp)[idx] = f2b(v); }
      }
    }
  }
}

// ------- per-segment KV sums via MFMA: mseg[v][d] = sum_s V[s][v]*sigK[s][d] -------
__global__ void kvsum_k(const unsigned short* __restrict__ KT, const unsigned short* __restrict__ VT,
                        float* __restrict__ memsegT, float* __restrict__ zseg) {
  __shared__ unsigned short As[128 * 32];
  __shared__ unsigned short Bs[128 * 32];
  const int seg = blockIdx.x, b = blockIdx.y, h = blockIdx.z;
  const int bh = b * 16 + h;
  const int t = threadIdx.x, wave = t >> 6, lane = t & 63;
  const int fr = lane & 15, fq = (lane >> 4) * 8;
  const int wr = (wave >> 1) * 64, wc = (wave & 1) * 64;

  f32x4 acc[4][4] = {};
  const size_t sbase = (size_t)seg * 512;
  const unsigned short* Ag = VT + ((size_t)(bh * 128 + wave * 32 + (lane >> 2)) << 12) + sbase + (lane & 3) * 8;
  const unsigned short* Bg = KT + ((size_t)(bh * 128 + wave * 32 + (lane >> 2)) << 12) + sbase + (lane & 3) * 8;
  unsigned short* Al = As + (wave * 32) * 32;
  unsigned short* Bl = Bs + (wave * 32) * 32;
  const size_t r16 = (size_t)16 << 12;

  for (int kk = 0; kk < 512; kk += 32) {
    __syncthreads();
    async16(Ag + kk, Al);
    async16(Ag + kk + r16, Al + 16 * 32);
    async16(Bg + kk, Bl);
    async16(Bg + kk + r16, Bl + 16 * 32);
    __syncthreads();
    s16x8 af[4], bfr[4];
    #pragma unroll
    for (int i = 0; i < 4; i++) af[i] = *(const s16x8*)&As[(wr + i * 16 + fr) * 32 + fq];
    #pragma unroll
    for (int j = 0; j < 4; j++) bfr[j] = *(const s16x8*)&Bs[(wc + j * 16 + fr) * 32 + fq];
    #pragma unroll
    for (int i = 0; i < 4; i++)
      #pragma unroll
      for (int j = 0; j < 4; j++)
        acc[i][j] = mfma16(af[i], bfr[j], acc[i][j]);
  }

  const size_t obase = (size_t)((seg * 2 + b) * 16 + h) * 16384;
  const int er = (lane >> 4) * 4, ec = lane & 15;
  #pragma unroll
  for (int i = 0; i < 4; i++)
    #pragma unroll
    for (int j = 0; j < 4; j++)
      #pragma unroll
      for (int r = 0; r < 4; r++)
        memsegT[obase + (size_t)(wr + i * 16 + er + r) * 128 + wc + j * 16 + ec] = acc[i][j][r];

  if (t < 128) {
    const unsigned short* zp = KT + ((size_t)(bh * 128 + t) << 12) + sbase;
    float z = 0.f;
    #pragma unroll 4
    for (int u = 0; u < 64; u++) {
      u16x8 kv = *(const u16x8*)(zp + u * 8);
      #pragma unroll
      for (int e = 0; e < 8; e++) z += b2f(kv[e]);
    }
    zseg[(size_t)((seg * 2 + b) * 16 + h) * 128 + t] = z;
  }
}

// ---------------- exclusive prefix over segments ----------------
__global__ void prefix_k(const float* __restrict__ memsegT, const float* __restrict__ zseg,
                         unsigned short* __restrict__ memPT, float* __restrict__ zP) {
  const int bh = blockIdx.x, t = threadIdx.x;
  for (int e = t; e < 16384; e += 256) {
    float a = 0.f;
    #pragma unroll
    for (int s = 0; s < 8; s++) {
      size_t idx = (size_t)(s * 32 + bh) * 16384 + e;
      memPT[idx] = f2b(a);
      a += memsegT[idx];
    }
  }
  if (t < 128) {
    float a = 1.f / 128.f;
    #pragma unroll
    for (int s = 0; s < 8; s++) {
      size_t idx = (size_t)(s * 32 + bh) * 128 + t;
      zP[idx] = a;
      a += zseg[idx];
    }
  }
}

// ---------------- fused segment attention (flash) + memory retrieval + gate ----------------
#define PD 136
#define PPS 40
__global__ void attn_k(const unsigned short* __restrict__ qb,
                       const unsigned short* __restrict__ kb,
                       const unsigned short* __restrict__ VT,
                       const unsigned short* __restrict__ memPT,
                       const float* __restrict__ zPv,
                       const float* __restrict__ betas,
                       unsigned short* __restrict__ att) {
  const int qt = blockIdx.x, seg = blockIdx.y, bh = blockIdx.z;
  const int b = bh >> 4, h = bh & 15;
  const int t = threadIdx.x, wave = t >> 6, lane = t & 63;
  const int fr = lane & 15, quad = lane >> 4, fq = quad * 8;

  __shared__ unsigned short Qs[64 * PD];
  __shared__ unsigned short SB[64 * PD];    // sig_q, later P
  __shared__ unsigned short KB[32 * PD];    // mem quarters / K tiles
  __shared__ unsigned short VTs[128 * PPS]; // V^T tile [v][s]
  __shared__ float denomS[64];
  __shared__ float dpart[4][64];
  __shared__ float zPs[128];

  unsigned short* SQ = SB;
  unsigned short* Ps = SB;

  const size_t qrow0 = (size_t)b * CS + (size_t)seg * CSEG + (size_t)qt * 64;
  const size_t mbase = (size_t)(seg * 32 + bh) * 16384;
  const size_t vtbase = ((size_t)(bh * 128) << 12) + (size_t)seg * 512;

  // stage Q (pre-scaled) and sig_q
  {
    int row = t >> 2, c0 = (t & 3) * 32;
    const unsigned short* src = qb + (qrow0 + row) * (size_t)CD + (size_t)h * 128 + c0;
    #pragma unroll
    for (int u = 0; u < 4; u++) {
      u16x8 qv = *(const u16x8*)(src + u * 8);
      u16x8 qo, so;
      #pragma unroll
      for (int e = 0; e < 8; e++) {
        float f = b2f(qv[e]);
        qo[e] = f2b(f * 0.08838834764831845f);
        so[e] = f2b(f > 0.f ? f + 1.f : __expf(f));
      }
      *(u16x8*)&Qs[row * PD + c0 + u * 8] = qo;
      *(u16x8*)&SQ[row * PD + c0 + u * 8] = so;
    }
    if (t < 128) zPs[t] = zPv[(size_t)(seg * 32 + bh) * 128 + t];
  }
  __syncthreads();

  // denominators: sig_q . zP (parallel over 4 chunks)
  {
    int row = t & 63, part = t >> 6;
    float s = 0.f;
    #pragma unroll
    for (int i = 0; i < 32; i++) {
      int d = part * 32 + i;
      s += b2f(SQ[row * PD + d]) * zPs[d];
    }
    dpart[part][row] = s;
  }
  __syncthreads();
  if (t < 64) denomS[t] = dpart[0][t] + dpart[1][t] + dpart[2][t] + dpart[3][t];

  // att_mem = sig_q @ memP  (memP staged in 32-row quarters)
  f32x4 om[8] = {};
  for (int qd = 0; qd < 4; qd++) {
    __syncthreads();
    {
      int row = t >> 3, c0 = (t & 7) * 16;
      const unsigned short* msrc = memPT + mbase + (size_t)(qd * 32 + row) * 128 + c0;
      *(u16x8*)&KB[row * PD + c0] = *(const u16x8*)msrc;
      *(u16x8*)&KB[row * PD + c0 + 8] = *(const u16x8*)(msrc + 8);
    }
    __syncthreads();
    #pragma unroll
    for (int jj = 0; jj < 2; jj++)
      #pragma unroll
      for (int kf = 0; kf < 4; kf++) {
        s16x8 a = *(const s16x8*)&SQ[(wave * 16 + fr) * PD + kf * 32 + fq];
        s16x8 bb = *(const s16x8*)&KB[(jj * 16 + fr) * PD + kf * 32 + fq];
        om[qd * 2 + jj] = mfma16(a, bb, om[qd * 2 + jj]);
      }
  }

  // causal attention, online softmax, 32-key tiles
  f32x4 od[8] = {};
  float mrow[4], lrow[4];
  #pragma unroll
  for (int r = 0; r < 4; r++) { mrow[r] = -1e30f; lrow[r] = 0.f; }

  const int nkt = qt * 2 + 2;
  for (int kt = 0; kt < nkt; kt++) {
    __syncthreads();
    {
      // K tile (normal layout) for scores
      int row = t >> 3, c0 = (t & 7) * 16;
      size_t g = ((size_t)b * CS + (size_t)seg * CSEG + (size_t)kt * 32 + row) * CD + (size_t)h * 128 + c0;
      *(u16x8*)&KB[row * PD + c0] = *(const u16x8*)(kb + g);
      *(u16x8*)&KB[row * PD + c0 + 8] = *(const u16x8*)(kb + g + 8);
      // V^T tile [128 v][32 s] from pre-transposed global (vector loads)
      int v = t >> 1, sc = (t & 1) * 16;
      const unsigned short* vsrc = VT + vtbase + ((size_t)v << 12) + kt * 32 + sc;
      *(u16x8*)&VTs[v * PPS + sc] = *(const u16x8*)vsrc;
      *(u16x8*)&VTs[v * PPS + sc + 8] = *(const u16x8*)(vsrc + 8);
    }
    __syncthreads();

    f32x4 sc[2] = {};
    #pragma unroll
    for (int kf = 0; kf < 4; kf++) {
      s16x8 a = *(const s16x8*)&Qs[(wave * 16 + fr) * PD + kf * 32 + fq];
      #pragma unroll
      for (int nt = 0; nt < 2; nt++) {
        s16x8 bb = *(const s16x8*)&KB[(nt * 16 + fr) * PD + kf * 32 + fq];
        sc[nt] = mfma16(a, bb, sc[nt]);
      }
    }

    if (kt >= 2 * qt) {
      #pragma unroll
      for (int nt = 0; nt < 2; nt++)
        #pragma unroll
        for (int r = 0; r < 4; r++) {
          int qi = qt * 64 + wave * 16 + quad * 4 + r;
          int ki = kt * 32 + nt * 16 + fr;
          if (ki > qi) sc[nt][r] = -1e30f;
        }
    }

    float al[4], pv[2][4];
    #pragma unroll
    for (int r = 0; r < 4; r++) {
      float mx = fmaxf(sc[0][r], sc[1][r]);
      #pragma unroll
      for (int xm = 8; xm >= 1; xm >>= 1) mx = fmaxf(mx, __shfl_xor(mx, xm, 64));
      float mn = fmaxf(mrow[r], mx);
      al[r] = __expf(mrow[r] - mn);
      mrow[r] = mn;
      float ps = 0.f;
      #pragma unroll
      for (int nt = 0; nt < 2; nt++) {
        float p = __expf(sc[nt][r] - mn);
        pv[nt][r] = p;
        ps += p;
      }
      #pragma unroll
      for (int xm = 8; xm >= 1; xm >>= 1) ps += __shfl_xor(ps, xm, 64);
      lrow[r] = lrow[r] * al[r] + ps;
    }
    #pragma unroll
    for (int j = 0; j < 8; j++)
      #pragma unroll
      for (int r = 0; r < 4; r++) od[j][r] *= al[r];

    #pragma unroll
    for (int nt = 0; nt < 2; nt++)
      #pragma unroll
      for (int r = 0; r < 4; r++)
        Ps[(wave * 16 + quad * 4 + r) * PPS + nt * 16 + fr] = f2b(pv[nt][r]);

    s16x8 a = *(const s16x8*)&Ps[(wave * 16 + fr) * PPS + fq];
    #pragma unroll
    for (int j = 0; j < 8; j++) {
      s16x8 bb = *(const s16x8*)&VTs[(j * 16 + fr) * PPS + fq];
      od[j] = mfma16(a, bb, od[j]);
    }
  }

  // gate-combine epilogue
  #pragma unroll
  for (int j = 0; j < 8; j++) {
    int vcol = j * 16 + fr;
    float g = 1.f / (1.f + __expf(-betas[h * 128 + vcol]));
    #pragma unroll
    for (int r = 0; r < 4; r++) {
      int rowl = wave * 16 + quad * 4 + r;
      float amem = om[j][r] / denomS[rowl];
      float adot = od[j][r] / lrow[r];
      att[(qrow0 + rowl) * (size_t)CD + (size_t)h * 128 + vcol] = f2b(g * amem + (1.f - g) * adot);
    }
  }
}

// ---------------- residual + LayerNorm (y in bf16) ----------------
__global__ void ln_k(const unsigned short* __restrict__ y, const float* __restrict__ x,
                     const float* __restrict__ gam, const float* __restrict__ bet,
                     float* __restrict__ out) {
  const int row = blockIdx.x, t = threadIdx.x;
  const int lane = t & 63, wave = t >> 6;
  const unsigned short* yr = y + (size_t)row * CD;
  const float* xr = x + (size_t)row * CD;
  float v[8];
  float s = 0.f, ss = 0.f;
  u16x8 a8 = *(const u16x8*)(yr + t * 8);
  #pragma unroll
  for (int u = 0; u < 2; u++) {
    f32x4 c = *(const f32x4*)(xr + t * 8 + u * 4);
    #pragma unroll
    for (int e = 0; e < 4; e++) {
      float r = b2f(a8[u * 4 + e]) + c[e];
      v[u * 4 + e] = r; s += r; ss += r * r;
    }
  }
  #pragma unroll
  for (int off = 32; off >= 1; off >>= 1) {
    s += __shfl_xor(s, off, 64);
    ss += __shfl_xor(ss, off, 64);
  }
  __shared__ float red[8];
  if (lane == 0) { red[wave] = s; red[4 + wave] = ss; }
  __syncthreads();
  s = red[0] + red[1] + red[2] + red[3];
  ss = red[4] + red[5] + red[6] + red[7];
  const float mu = s * (1.f / 2048.f);
  const float var = ss * (1.f / 2048.f) - mu * mu;
  const float rs = rsqrtf(var + 1e-5f);
  #pragma unroll
  for (int u = 0; u < 2; u++)
    #pragma unroll
    for (int e = 0; e < 4; e++) {
      int c = t * 8 + u * 4 + e;
      out[(size_t)row * CD + c] = (v[u * 4 + e] - mu) * rs * gam[c] + bet[c];
    }
}

extern "C" void kernel_launch(void* const* d_in, const int* in_sizes, int n_in,
                              void* d_out, int out_size, void* d_ws, size_t ws_size,
                              hipStream_t stream) {
  const float* xf   = (const float*)d_in[0];
  const float* Wq   = (const float*)d_in[1];
  const float* Wk   = (const float*)d_in[2];
  const float* Wv   = (const float*)d_in[3];
  const float* Wo   = (const float*)d_in[4];
  const float* bet  = (const float*)d_in[5];
  const float* W1   = (const float*)d_in[6];
  const float* b1   = (const float*)d_in[7];
  const float* W2   = (const float*)d_in[8];
  const float* b2   = (const float*)d_in[9];
  const float* lng  = (const float*)d_in[10];
  const float* lnb  = (const float*)d_in[11];
  float* out = (float*)d_out;

  // ---- 224 MB workspace, lifetime-overlaid ----
  const size_t MB = 1024ull * 1024ull;
  char* w = (char*)d_ws;
  unsigned short* qbuf  = (unsigned short*)(w + 0 * MB);    // dead after attn
  unsigned short* kbuf  = (unsigned short*)(w + 32 * MB);   // dead after attn
  unsigned short* vbuf  = (unsigned short*)(w + 64 * MB);   // dead after transpose_kv
  unsigned short* xb    = (unsigned short*)(w + 96 * MB);   // dead after QKV gemms
  unsigned short* VTg   = (unsigned short*)(w + 96 * MB);   // overlays xb; dead after attn
  unsigned short* KTg   = (unsigned short*)(w + 128 * MB);  // dead after kvsum
  unsigned short* attb  = (unsigned short*)(w + 128 * MB);  // overlays KTg
  float*          msegT = (float*)(w + 64 * MB);            // overlays vbuf (16MB)
  unsigned short* memPT = (unsigned short*)(w + 80 * MB);   // 8MB
  float*          zsegb = (float*)(w + 88 * MB);
  float*          zPb   = (float*)(w + 89 * MB);
  unsigned short* aob   = (unsigned short*)(w + 0 * MB);    // overlays qbuf (post-attn)
  unsigned short* hb    = (unsigned short*)(w + 32 * MB);   // 128MB: overlays kbuf..attb (post-Wo)
  unsigned short* ybb   = (unsigned short*)(w + 0 * MB);    // overlays aob (post-W1)
  unsigned short* W1T   = (unsigned short*)(w + 160 * MB);  // dead after W1 gemm
  unsigned short* W2T   = (unsigned short*)(w + 160 * MB);  // overlays W1T (post-W1)
  unsigned short* WqT   = (unsigned short*)(w + 192 * MB);
  unsigned short* WkT   = (unsigned short*)(w + 200 * MB);
  unsigned short* WvT   = (unsigned short*)(w + 208 * MB);
  unsigned short* WoT   = (unsigned short*)(w + 216 * MB);

  convert_bf16_k<<<dim3(16384), 256, 0, stream>>>(xf, xb);
  transpose_bf16_k<<<dim3(64, 64), 256, 0, stream>>>(Wq, WqT, 2048, 2048);
  transpose_bf16_k<<<dim3(64, 64), 256, 0, stream>>>(Wk, WkT, 2048, 2048);
  transpose_bf16_k<<<dim3(64, 64), 256, 0, stream>>>(Wv, WvT, 2048, 2048);
  transpose_bf16_k<<<dim3(64, 64), 256, 0, stream>>>(Wo, WoT, 2048, 2048);
  transpose_bf16_k<<<dim3(256, 64), 256, 0, stream>>>(W1, W1T, 2048, 8192);

  gemm_bt<1><<<dim3(64, 16), 256, 0, stream>>>(xb, WqT, nullptr, qbuf, 8192, 2048, 2048);
  gemm_bt<1><<<dim3(64, 16), 256, 0, stream>>>(xb, WkT, nullptr, kbuf, 8192, 2048, 2048);
  gemm_bt<1><<<dim3(64, 16), 256, 0, stream>>>(xb, WvT, nullptr, vbuf, 8192, 2048, 2048);

  transpose_kv_k<<<dim3(128, 32), 256, 0, stream>>>(kbuf, vbuf, KTg, VTg);
  kvsum_k<<<dim3(8, 2, 16), 256, 0, stream>>>(KTg, VTg, msegT, zsegb);
  prefix_k<<<dim3(32), 256, 0, stream>>>(msegT, zsegb, memPT, zPb);
  attn_k<<<dim3(8, 8, 32), 256, 0, stream>>>(qbuf, kbuf, VTg, memPT, zPb, bet, attb);

  gemm_bt<1><<<dim3(64, 16), 256, 0, stream>>>(attb, WoT, nullptr, aob, 8192, 2048, 2048);
  gemm_bt<2><<<dim3(64, 64), 256, 0, stream>>>(aob, W1T, b1, hb, 8192, 8192, 2048);
  transpose_bf16_k<<<dim3(64, 256), 256, 0, stream>>>(W2, W2T, 8192, 2048);
  gemm_bt<4><<<dim3(64, 16), 256, 0, stream>>>(hb, W2T, b2, ybb, 8192, 2048, 8192);
  ln_k<<<dim3(8192), 256, 0, stream>>>(ybb, xf, lng, lnb, out);
}